// Round 14
// baseline (451.504 us; speedup 1.0000x reference)
//
#include <hip/hip_runtime.h>
#include <math.h>

#define NF 65536
#define NE 1024
#define ED 64
#define KBOT 32768
#define RTOP 65472            // NF - 64
#define BINS 2048
#define CAPB 2048
#define CAPT 1024
#define CAP3 256
#define ZSTRIDE 17            // float4 row stride in init staging (68 floats, 16B aligned)

typedef float nvec4 __attribute__((ext_vector_type(4)));

static const long long OFF_LOSS   = 0;
static const long long OFF_LOSS1  = 1;
static const long long OFF_LOSS2  = 2;
static const long long OFF_ZQST   = 3;
static const long long OFF_ZOUT   = 3LL + 4194304LL;       // 4194307
static const long long OFF_PERP   = 3LL + 8388608LL;       // 8388611
static const long long OFF_MINENC = 8388612LL;             // 16B aligned (x4)
static const long long OFF_IDX    = 75497476LL;            // 16B aligned (x4)
static const long long OFF_NEP    = 75563012LL;
static const long long OFF_NEMB   = 75564036LL;
// scratch in out:  cn = out+OFF_IDX (256KB, overwritten by idx floats)
//                  dT = out+OFF_MINENC (268MB, zeroed by colstats -> min_encodings)
// scratch in ws:   accs@0, counts@64, anchor@8192, done@12288, norms@65536, rowkey8@1MB
// R14: colstats column held in registers (float4 vreg[16]) -> single dT read,
// no pass-2 re-read (R5's L3-reuse fragility eliminated structurally).

__device__ __forceinline__ unsigned ordf(float v){
  unsigned u = __float_as_uint(v);
  return (u & 0x80000000u) ? ~u : (u | 0x80000000u);
}

// Replicates np.linalg.norm for a 64-elem row (pairwise-8 order), sqrt, max(,1e-12).
__device__ __forceinline__ float np_l2norm_row(const float* __restrict__ x){
  float r[8];
  #pragma unroll
  for (int j=0;j<8;j++){ float t=x[j]; r[j]=__fmul_rn(t,t); }
  #pragma unroll
  for (int b=1;b<8;b++){
    #pragma unroll
    for (int j=0;j<8;j++){ float t=x[b*8+j]; r[j]=__fadd_rn(r[j], __fmul_rn(t,t)); }
  }
  float s = __fadd_rn(__fadd_rn(__fadd_rn(r[0],r[1]),__fadd_rn(r[2],r[3])),
                      __fadd_rn(__fadd_rn(r[4],r[5]),__fadd_rn(r[6],r[7])));
  float nr = __fsqrt_rn(s);
  return fmaxf(nr, 1e-12f);
}

// blocks 0..255: LDS-staged coalesced z row-norms (256 rows/block).
// blocks 256..259: emb normalization into cn + zeroing first 16KB of ws.
__global__ __launch_bounds__(256) void init_kernel(const float* __restrict__ z,
        const float* __restrict__ emb, float* __restrict__ norms,
        float* __restrict__ cn, float* __restrict__ wszero){
  __shared__ float4 zl[256*ZSTRIDE];     // 69,632 B
  const int tid = threadIdx.x;
  if (blockIdx.x < 256){
    const float4* zg = (const float4*)(z + (size_t)blockIdx.x*256*ED);
    #pragma unroll
    for (int i=0;i<16;i++){
      int g = i*256 + tid;               // 0..4095, coalesced
      int row = g>>4, q = g&15;
      zl[row*ZSTRIDE + q] = zg[g];
    }
    __syncthreads();
    const float* xr = (const float*)&zl[tid*ZSTRIDE];
    norms[blockIdx.x*256 + tid] = np_l2norm_row(xr);
  } else {
    int eb = blockIdx.x - 256;           // 0..3
    ((float4*)wszero)[eb*256 + tid] = make_float4(0.f,0.f,0.f,0.f);
    int n = eb*256 + tid;                // < 1024
    float xv[ED];
    const float4* xg = (const float4*)(emb + (size_t)n*ED);
    #pragma unroll
    for (int i=0;i<16;i++) *(float4*)&xv[i*4] = xg[i];
    float nr = np_l2norm_row(xv);
    float4* o = (float4*)(cn + (size_t)n*ED);
    #pragma unroll
    for (int i=0;i<16;i++){
      float4 v;
      v.x=__fdiv_rn(xv[i*4+0],nr); v.y=__fdiv_rn(xv[i*4+1],nr);
      v.z=__fdiv_rn(xv[i*4+2],nr); v.w=__fdiv_rn(xv[i*4+3],nr);
      o[i]=v;
    }
  }
}

// d = zn @ cn^T (65536x1024, K=64) stored transposed dT[c][r].
// LDS-tiled 128x128, 8x8 register blocking, XOR-swizzled LDS, LDS-transposed
// coalesced column stores (R8). z normalized in-staging (bit-exact).
__global__ __launch_bounds__(256) void gemm_kernel(const float* __restrict__ z,
      const float* __restrict__ norms,
      const float* __restrict__ cn, float* __restrict__ dT,
      unsigned long long* __restrict__ rowkey8){
  __shared__ float4 zsh[128*16];   // [r][slot], slot = q ^ ((r>>3)&7); reused as transpose tile
  __shared__ float4 wsh[128*16];   // [c][slot], slot = q ^ (c&7)
  const int tid = threadIdx.x;
  const int rblk = blockIdx.x >> 3;          // 0..511
  const int cblk = blockIdx.x & 7;           // 0..7
  const int r0 = rblk*128, c0g = cblk*128;

  const float4* zg = (const float4*)(z + (size_t)r0*ED);
  const float4* wg = (const float4*)(cn + (size_t)c0g*ED);
  #pragma unroll
  for (int i=0;i<8;i++){
    int di = i*256 + tid;                    // float4 slot 0..2047
    int c = di>>4, q = di&15;
    wsh[di] = wg[c*16 + (q ^ (c&7))];
    float4 zv4 = zg[c*16 + (q ^ ((c>>3)&7))];
    float nr = norms[r0 + c];
    zv4.x=__fdiv_rn(zv4.x,nr); zv4.y=__fdiv_rn(zv4.y,nr);
    zv4.z=__fdiv_rn(zv4.z,nr); zv4.w=__fdiv_rn(zv4.w,nr);
    zsh[di] = zv4;
  }
  __syncthreads();

  const int l  = tid & 63;
  const int wv = tid >> 6;
  const int rg = l >> 4;                     // 0..3
  const int cl = l & 15;                     // 0..15
  const int rowb = wv*32 + rg*8;             // lane's 8 consecutive local rows
  const int zsw = ((rowb>>3)&7);
  const int sw = cl & 7;

  float acc[8][8];
  #pragma unroll
  for (int r=0;r<8;r++)
    #pragma unroll
    for (int j=0;j<8;j++) acc[r][j]=0.0f;

  for (int q=0;q<16;q++){
    float4 zv[8], wvv[8];
    #pragma unroll
    for (int r=0;r<8;r++){
      int row = rowb + r;
      zv[r] = zsh[row*16 + (q ^ zsw)];
    }
    #pragma unroll
    for (int j=0;j<8;j++){
      int c = cl + 16*j;
      wvv[j] = wsh[c*16 + (q ^ sw)];
    }
    #pragma unroll
    for (int r=0;r<8;r++){
      #pragma unroll
      for (int j=0;j<8;j++){
        float a = acc[r][j];
        a = fmaf(zv[r].x, wvv[j].x, a);
        a = fmaf(zv[r].y, wvv[j].y, a);
        a = fmaf(zv[r].z, wvv[j].z, a);
        a = fmaf(zv[r].w, wvv[j].w, a);
        acc[r][j] = a;
      }
    }
  }

  // ---- coalesced transposed store via LDS (4 chunks of 32 columns) ----
  float4* tsh = zsh;                         // [colL][33] float4
  #pragma unroll
  for (int chunk=0;chunk<4;chunk++){
    __syncthreads();
    #pragma unroll
    for (int j2=0;j2<2;j2++){
      int j = chunk*2 + j2;
      int colL = cl + 16*j2;
      tsh[colL*33 + (rowb>>2)]     = make_float4(acc[0][j],acc[1][j],acc[2][j],acc[3][j]);
      tsh[colL*33 + (rowb>>2) + 1] = make_float4(acc[4][j],acc[5][j],acc[6][j],acc[7][j]);
    }
    __syncthreads();
    #pragma unroll
    for (int i=0;i<4;i++){
      int f = tid + 256*i;                   // 0..1023
      int colL = f >> 5, r4 = f & 31;
      int col = c0g + chunk*32 + colL;
      *(float4*)(dT + (size_t)col*NF + r0 + 4*r4) = tsh[colL*33 + r4];
    }
  }

  #pragma unroll
  for (int r=0;r<8;r++){
    float bv = acc[r][0]; int bc = c0g + cl;
    #pragma unroll
    for (int j=1;j<8;j++){
      int c = c0g + cl + 16*j;
      if (acc[r][j] > bv){ bv = acc[r][j]; bc = c; }
    }
    unsigned long long key = ((unsigned long long)ordf(bv)<<32) |
                             (unsigned long long)(0xFFFFFFFFu - (unsigned)bc);
    #pragma unroll
    for (int m=1;m<16;m<<=1){
      unsigned long long o = __shfl_xor(key, m);
      if (o > key) key = o;
    }
    if (cl==0) rowkey8[(size_t)(r0 + rowb + r)*8 + cblk] = key;
  }
}

// Merged dispatch: blocks 0..1023 = colstats (register-resident column,
// single dT read, sortless selection, fused nontemporal zero-write).
// blocks 1024..2047 = zq work.
__global__ __launch_bounds__(1024) void colstats_zq_kernel(float* __restrict__ dT,
        int* __restrict__ anchor, double* __restrict__ accs,
        const float* __restrict__ z, const float* __restrict__ emb,
        const unsigned long long* __restrict__ rowkey8,
        int* __restrict__ counts, float* __restrict__ out){
  __shared__ unsigned hist[BINS];
  __shared__ float bufB[CAPB];
  __shared__ float bufT[CAPT];
  __shared__ float bndry[CAP3];
  __shared__ unsigned wtot[16];
  __shared__ float wred[16];
  __shared__ float s_m0f;
  __shared__ int s_anch;
  __shared__ int s_binB, s_cbelow, s_binT;
  __shared__ int s_cntB, s_cntT, s_cnt3;
  __shared__ int s_binB2, s_cb2, s_binT2, s_ca2;
  __shared__ float s_Ebelow, s_EbinPre, s_acc3B, s_TopPre, s_acc3T;

  const int tid = threadIdx.x;
  const int lane = tid & 63;
  const int wid = tid >> 6;           // 0..15

  if (blockIdx.x >= 1024){
    // ================= zq branch =================
    const int gid = (blockIdx.x - 1024)*1024 + tid;   // < 1048576 float4 units
    const int f = gid >> 4;
    const int sub = gid & 15;
    int c = 0;
    if (sub == 0){
      const unsigned long long* rk = rowkey8 + (size_t)f*8;
      unsigned long long K = rk[0];
      #pragma unroll
      for (int w=1;w<8;w++){
        unsigned long long o = rk[w];
        if (o > K) K = o;
      }
      c = (int)(0xFFFFFFFFu - (unsigned)(K & 0xFFFFFFFFull));
      out[OFF_IDX + f] = (float)c;
      atomicAdd(&counts[c], 1);
    }
    c = __shfl(c, lane & ~15);
    const int e0 = sub*4;
    const float4 q = *(const float4*)(emb + (size_t)c*ED + e0);
    const float4 zv = ((const float4*)z)[gid];
    float dx=__fsub_rn(q.x,zv.x), dy=__fsub_rn(q.y,zv.y);
    float dz2=__fsub_rn(q.z,zv.z), dw=__fsub_rn(q.w,zv.w);
    float ox=__fadd_rn(zv.x,dx), oy=__fadd_rn(zv.y,dy);
    float oz=__fadd_rn(zv.z,dz2), ow=__fadd_rn(zv.w,dw);
    size_t base = (size_t)gid*4;
    float* zq = out + OFF_ZQST; float* zo = out + OFF_ZOUT;
    zq[base+0]=ox; zq[base+1]=oy; zq[base+2]=oz; zq[base+3]=ow;
    zo[base+0]=ox; zo[base+1]=oy; zo[base+2]=oz; zo[base+3]=ow;
    float ls = __fadd_rn(__fadd_rn(__fmul_rn(dx,dx),__fmul_rn(dy,dy)),
                         __fadd_rn(__fmul_rn(dz2,dz2),__fmul_rn(dw,dw)));
    #pragma unroll
    for (int off=32;off;off>>=1) ls += __shfl_down(ls, off);
    if (lane==0) wred[wid]=ls;
    __syncthreads();
    if (tid==0){
      float t=wred[0];
      #pragma unroll
      for (int w=1;w<16;w++) t+=wred[w];
      atomicAdd(&accs[0], (double)t);
    }
    return;
  }

  // ================= colstats branch =================
  const int n = blockIdx.x;
  float* __restrict__ p = dT + (size_t)n*NF;
  const float4* __restrict__ p4c = (const float4*)p;

  hist[tid]=0u; hist[tid+1024]=0u;
  if (tid==0){ s_cntB=0; s_cntT=0; s_anch=0x7FFFFFFF; }
  __syncthreads();

  // ---- single read: column -> registers ----
  float4 vreg[16];
  #pragma unroll
  for (int t=0;t<16;t++) vreg[t] = p4c[tid + t*1024];

  // ---- pass 1 (from regs): histogram + max ----
  float mx = -INFINITY;
  #pragma unroll
  for (int t=0;t<16;t++){
    float4 v4 = vreg[t];
    #pragma unroll
    for (int c=0;c<4;c++){
      float v = (c==0)?v4.x:(c==1)?v4.y:(c==2)?v4.z:v4.w;
      mx = fmaxf(mx, v);
      int b = (int)((v+1.0f)*1024.0f);
      b = b<0?0:(b>BINS-1?BINS-1:b);
      atomicAdd(&hist[b],1u);
    }
  }
  #pragma unroll
  for (int off=32;off;off>>=1) mx = fmaxf(mx, __shfl_down(mx, off));
  if (lane==0) wred[wid]=mx;
  __syncthreads();
  if (tid==0){
    float t=wred[0];
    #pragma unroll
    for (int w=1;w<16;w++) t=fmaxf(t,wred[w]);
    s_m0f = t;
  }

  // ---- level-1 scan over bin-pairs (2 syncs) ----
  const unsigned h0 = hist[2*tid], h1 = hist[2*tid+1];
  const unsigned c2 = h0+h1;
  unsigned x = c2;
  #pragma unroll
  for (int off=1;off<64;off<<=1){
    unsigned y = __shfl_up(x, off);
    if (lane >= off) x += y;
  }
  if (lane==63) wtot[wid] = x;
  __syncthreads();
  if (wid==0 && lane<16){
    unsigned t = wtot[lane];
    #pragma unroll
    for (int off=1;off<16;off<<=1){
      unsigned y = __shfl_up(t, off);
      if (lane >= off) t += y;
    }
    wtot[lane] = t;
  }
  __syncthreads();
  const unsigned inc1 = x + (wid>0 ? wtot[wid-1] : 0u);
  {
    const unsigned pre = inc1 - c2;
    if (pre < (unsigned)KBOT && pre+h0 >= (unsigned)KBOT){ s_binB=2*tid;   s_cbelow=(int)pre; }
    else if (pre+h0 < (unsigned)KBOT && inc1 >= (unsigned)KBOT){ s_binB=2*tid+1; s_cbelow=(int)(pre+h0); }
    if (pre <= (unsigned)RTOP && (unsigned)RTOP < pre+h0) s_binT=2*tid;
    else if (pre+h0 <= (unsigned)RTOP && (unsigned)RTOP < inc1) s_binT=2*tid+1;
  }
  __syncthreads();

  // ---- pass 2 (from regs): E_below + gather + anchor + zero-write ----
  const int binB=s_binB, binT=s_binT;
  const float m0=s_m0f;
  const float LINV = 1.0f/0.07f;
  nvec4 zz = (nvec4)(0.0f);
  nvec4* p4w = (nvec4*)p;
  float es=0.0f;
  #pragma unroll
  for (int t=0;t<16;t++){
    float4 v4 = vreg[t];
    __builtin_nontemporal_store(zz, &p4w[tid + t*1024]);
    int base = (tid + t*1024)*4;
    #pragma unroll
    for (int c=0;c<4;c++){
      float v = (c==0)?v4.x:(c==1)?v4.y:(c==2)?v4.z:v4.w;
      int b=(int)((v+1.0f)*1024.0f);
      b=b<0?0:(b>BINS-1?BINS-1:b);
      if (b<binB) es += __expf((v-m0)*LINV);
      if (b==binB){ int pos=atomicAdd(&s_cntB,1); if (pos<CAPB) bufB[pos]=v; }
      if (b>=binT){ int pos=atomicAdd(&s_cntT,1); if (pos<CAPT) bufT[pos]=v; }
      if (v==m0) atomicMin(&s_anch, base+c);
    }
  }
  hist[tid]=0u; hist[tid+1024]=0u;
  #pragma unroll
  for (int off=32;off;off>>=1) es += __shfl_down(es, off);
  if (lane==0) wred[wid]=es;
  __syncthreads();
  if (tid==0){
    float t=wred[0];
    #pragma unroll
    for (int w=1;w<16;w++) t+=wred[w];
    s_Ebelow=t;
    s_cnt3=0; s_binB2=0; s_cb2=0; s_acc3B=0.0f; s_acc3T=0.0f;
  }
  __syncthreads();

  // ---- level-2 bottom ----
  const int cntB = (s_cntB<CAPB)?s_cntB:CAPB;
  int m = KBOT - s_cbelow; if (m>cntB) m=cntB; if (m<0) m=0;
  const float loB = (float)binB*(1.0f/1024.0f) - 1.0f;
  float* fsum = (float*)&hist[1024];
  for (int i=tid;i<cntB;i+=1024){
    float v=bufB[i];
    int sub=(int)((v-loB)*1048576.0f);
    sub = sub<0?0:(sub>1023?1023:sub);
    atomicAdd(&hist[sub],1u);
    atomicAdd(&fsum[sub], __expf((v-m0)*LINV));
  }
  __syncthreads();
  {
    unsigned cb = hist[tid];
    unsigned xb = cb;
    #pragma unroll
    for (int off=1;off<64;off<<=1){
      unsigned y = __shfl_up(xb, off);
      if (lane >= off) xb += y;
    }
    if (lane==63) wtot[wid]=xb;
    __syncthreads();
    if (wid==0 && lane<16){
      unsigned t = wtot[lane];
      #pragma unroll
      for (int off=1;off<16;off<<=1){
        unsigned y = __shfl_up(t, off);
        if (lane >= off) t += y;
      }
      wtot[lane]=t;
    }
    __syncthreads();
    unsigned incb = xb + (wid>0? wtot[wid-1]:0u);
    unsigned preb = incb - cb;
    if (m>0 && preb < (unsigned)m && incb >= (unsigned)m){ s_binB2=tid; s_cb2=(int)preb; }
  }
  __syncthreads();
  {
    float ep = (tid < s_binB2)? fsum[tid] : 0.0f;
    #pragma unroll
    for (int off=32;off;off>>=1) ep += __shfl_down(ep, off);
    if (lane==0) wred[wid]=ep;
    __syncthreads();
    if (tid==0){
      float t=wred[0];
      #pragma unroll
      for (int w=1;w<16;w++) t+=wred[w];
      s_EbinPre=t;
    }
  }
  const int binB2=s_binB2;
  const int m2v = m - s_cb2;
  for (int i=tid;i<cntB;i+=1024){
    float v=bufB[i];
    int sub=(int)((v-loB)*1048576.0f);
    sub = sub<0?0:(sub>1023?1023:sub);
    if (sub==binB2){ int pos=atomicAdd(&s_cnt3,1); if (pos<CAP3) bndry[pos]=v; }
  }
  __syncthreads();
  if (wid==0){
    int cnt3 = (s_cnt3<CAP3)?s_cnt3:CAP3;
    int m2 = m2v; if (m2>cnt3) m2=cnt3; if (m2<0) m2=0;
    float acc3=0.0f;
    for (int it=0; it<m2; ++it){
      unsigned long long key = 0ull;
      for (int i=lane;i<cnt3;i+=64){
        float v=bndry[i];
        unsigned long long k = ((unsigned long long)(0xFFFFFFFFu - ordf(v))<<32) | (unsigned)i;
        if (k>key) key=k;
      }
      #pragma unroll
      for (int off=32;off;off>>=1){
        unsigned long long o = __shfl_xor(key, off);
        if (o>key) key=o;
      }
      int idx = (int)(key & 0xFFFFFFFFull);
      if (lane==0){
        float v = bndry[idx];
        acc3 += __expf((v-m0)*LINV);
        bndry[idx] = __uint_as_float(0x7f800000u);
      }
    }
    if (lane==0) s_acc3B = acc3;
  }
  hist[tid]=0u; hist[tid+1024]=0u;
  if (tid==1023) s_cnt3=0;
  __syncthreads();

  // ---- level-2 top ----
  const int cntT = (s_cntT<CAPT)?s_cntT:CAPT;
  const float loT = (float)binT*(1.0f/1024.0f) - 1.0f;
  float rngT = m0 - loT;
  float scaleT = (rngT > 1e-30f)? (1023.0f/rngT) : 0.0f;
  for (int i=tid;i<cntT;i+=1024){
    float v=bufT[i];
    int sub=(int)((v-loT)*scaleT);
    sub = sub<0?0:(sub>1023?1023:sub);
    atomicAdd(&hist[sub],1u);
    atomicAdd(&fsum[sub], v);
  }
  __syncthreads();
  {
    unsigned ct = hist[tid];
    unsigned xt = ct;
    #pragma unroll
    for (int off=1;off<64;off<<=1){
      unsigned y = __shfl_up(xt, off);
      if (lane >= off) xt += y;
    }
    if (lane==63) wtot[wid]=xt;
    __syncthreads();
    if (wid==0 && lane<16){
      unsigned t = wtot[lane];
      #pragma unroll
      for (int off=1;off<16;off<<=1){
        unsigned y = __shfl_up(t, off);
        if (lane >= off) t += y;
      }
      wtot[lane]=t;
    }
    __syncthreads();
    unsigned inct = xt + (wid>0? wtot[wid-1]:0u);
    unsigned above = (unsigned)cntT - inct;
    if (above < 64u && above + ct >= 64u){ s_binT2=tid; s_ca2=(int)above; }
  }
  __syncthreads();
  {
    float tv = (tid > s_binT2)? fsum[tid] : 0.0f;
    #pragma unroll
    for (int off=32;off;off>>=1) tv += __shfl_down(tv, off);
    if (lane==0) wred[wid]=tv;
    __syncthreads();
    if (tid==0){
      float t=wred[0];
      #pragma unroll
      for (int w=1;w<16;w++) t+=wred[w];
      s_TopPre=t;
    }
  }
  const int binT2=s_binT2;
  const int need2v = 64 - s_ca2;
  for (int i=tid;i<cntT;i+=1024){
    float v=bufT[i];
    int sub=(int)((v-loT)*scaleT);
    sub = sub<0?0:(sub>1023?1023:sub);
    if (sub==binT2){ int pos=atomicAdd(&s_cnt3,1); if (pos<CAP3) bndry[pos]=v; }
  }
  __syncthreads();
  if (wid==0){
    int cnt3 = (s_cnt3<CAP3)?s_cnt3:CAP3;
    int need2 = need2v; if (need2>cnt3) need2=cnt3; if (need2<0) need2=0;
    float acc3=0.0f;
    for (int it=0; it<need2; ++it){
      unsigned long long key = 0ull;
      for (int i=lane;i<cnt3;i+=64){
        float v=bndry[i];
        unsigned long long k = ((unsigned long long)ordf(v)<<32) | (unsigned)i;
        if (k>key) key=k;
      }
      #pragma unroll
      for (int off=32;off;off>>=1){
        unsigned long long o = __shfl_xor(key, off);
        if (o>key) key=o;
      }
      int idx = (int)(key & 0xFFFFFFFFull);
      if (lane==0){
        acc3 += bndry[idx];
        bndry[idx] = __uint_as_float(0xff800000u);
      }
    }
    if (lane==0) s_acc3T = acc3;
  }
  __syncthreads();
  if (tid==0){
    float topSum = s_TopPre + s_acc3T;
    float dis_pos = topSum*(1.0f/64.0f);
    float S = (s_Ebelow + s_EbinPre + s_acc3B)*expf((m0-dis_pos)*LINV);
    atomicAdd(&accs[1], (double)log1pf(S));
    anchor[n] = s_anch;
  }
}

// blocks 0..255: codebook update (4 columns per block).
// blocks 256..511: one-hot scatter. Last block to finish runs finalize.
__global__ __launch_bounds__(256) void codebook_scatter_kernel(const float* __restrict__ emb,
     const float* __restrict__ eprob, const float* __restrict__ z,
     const int* __restrict__ counts, const int* __restrict__ anchor,
     float* __restrict__ out, double* __restrict__ accs, unsigned* __restrict__ done){
  const int b = blockIdx.x;
  if (b < 256){
    const int n = b*4 + (threadIdx.x>>6);
    const int e = threadIdx.x & 63;
    float em = (float)counts[n] * (1.0f/65536.0f);
    float nep = __fadd_rn(__fmul_rn(eprob[n],0.99f), __fmul_rn(em,0.01f));
    if (e==0){
      out[OFF_NEP + n] = nep;
      atomicAdd(&accs[2], (double)__fmul_rn(em, logf(__fadd_rn(em,1e-10f))));
    }
    float t = __fmul_rn(__fmul_rn(nep,1024.0f),10.0f);
    t = __fdiv_rn(-t, 0.01f);
    t = __fsub_rn(t, 0.001f);
    float dec = expf(t);
    float onem = __fsub_rn(1.0f, dec);
    int a = anchor[n];
    float nv = __fadd_rn(__fmul_rn(emb[(size_t)n*ED+e], onem),
                         __fmul_rn(z[(size_t)a*ED+e], dec));
    out[OFF_NEMB + (size_t)n*ED + e] = nv;
  } else {
    int f = (b-256)*256 + threadIdx.x;       // < 65536
    int c = (int)out[OFF_IDX + f];
    out[OFF_MINENC + (size_t)f*NE + c] = 1.0f;
  }
  // ---- last-block finalize ----
  __syncthreads();
  if (threadIdx.x==0){
    __threadfence();
    unsigned prev = atomicAdd(done, 1u);
    if (prev == 511u){
      __threadfence();
      volatile double* va = accs;
      double a0 = va[0], a1 = va[1], a2 = va[2];
      float l1 = (float)(a0 / 4194304.0);
      float contra = (float)(a1 / 1024.0);
      out[OFF_LOSS1]=l1; out[OFF_LOSS2]=l1;
      out[OFF_LOSS]=__fadd_rn(__fadd_rn(__fmul_rn(1.0f,l1), __fmul_rn(0.25f,l1)), contra);
      out[OFF_PERP]=expf(-(float)a2);
    }
  }
}

extern "C" void kernel_launch(void* const* d_in, const int* in_sizes, int n_in,
                              void* d_out, int out_size, void* d_ws, size_t ws_size,
                              hipStream_t stream){
  (void)in_sizes; (void)n_in; (void)out_size; (void)ws_size;
  const float* z    = (const float*)d_in[0];
  const float* emb  = (const float*)d_in[1];
  const float* eprb = (const float*)d_in[2];
  float* out = (float*)d_out;
  char* ws = (char*)d_ws;
  double* accs = (double*)ws;                 // [0]=lossSum [1]=contraSum [2]=perpSum
  int* counts = (int*)(ws + 64);              // 1024 ints
  int* anchor = (int*)(ws + 8192);            // 1024 ints
  unsigned* done = (unsigned*)(ws + 12288);   // finalize counter (zeroed by init)
  float* norms = (float*)(ws + 65536);        // 65536 floats (256KB)
  unsigned long long* rowkey8 = (unsigned long long*)(ws + (1<<20));  // 4MB
  float* cn = out + OFF_IDX;                  // scratch (overwritten by idx floats)
  float* dT = out + OFF_MINENC;               // scratch (becomes min_encodings)

  hipLaunchKernelGGL(init_kernel, dim3(260), dim3(256), 0, stream, z, emb, norms, cn, (float*)ws);
  hipLaunchKernelGGL(gemm_kernel, dim3(4096), dim3(256), 0, stream, z, norms, cn, dT, rowkey8);
  hipLaunchKernelGGL(colstats_zq_kernel, dim3(2048), dim3(1024), 0, stream,
                     dT, anchor, accs, z, emb, rowkey8, counts, out);
  hipLaunchKernelGGL(codebook_scatter_kernel, dim3(512), dim3(256), 0, stream,
                     emb, eprb, z, counts, anchor, out, accs, done);
}

// Round 15
// 300.815 us; speedup vs baseline: 1.5009x; 1.5009x over previous
//
#include <hip/hip_runtime.h>
#include <math.h>

#define NF 65536
#define NE 1024
#define ED 64
#define KBOT 32768
#define RTOP 65472            // NF - 64
#define BINS 2048
#define CAPB 2048
#define CAPT 1024
#define CAP3 256
#define ZSTRIDE 17            // float4 row stride in init staging (68 floats, 16B aligned)

typedef float nvec4 __attribute__((ext_vector_type(4)));

static const long long OFF_LOSS   = 0;
static const long long OFF_LOSS1  = 1;
static const long long OFF_LOSS2  = 2;
static const long long OFF_ZQST   = 3;
static const long long OFF_ZOUT   = 3LL + 4194304LL;       // 4194307
static const long long OFF_PERP   = 3LL + 8388608LL;       // 8388611
static const long long OFF_MINENC = 8388612LL;             // 16B aligned (x4)
static const long long OFF_IDX    = 75497476LL;            // 16B aligned (x4)
static const long long OFF_NEP    = 75563012LL;
static const long long OFF_NEMB   = 75564036LL;
// scratch in out:  cn = out+OFF_IDX (256KB, overwritten by idx floats)
//                  dT = out+OFF_MINENC (268MB, zeroed by colstats -> min_encodings)
// scratch in ws:   accs@0, counts@64, anchor@8192, done@12288, norms@65536, rowkey8@1MB
// R15: pure revert to R13 (R14's register-resident column spilled to scratch:
// VGPR capped at 64 by launch_bounds(1024), +170us). Two-pass strided streams
// + __expf + last-block finalize. 4 dispatches.

__device__ __forceinline__ unsigned ordf(float v){
  unsigned u = __float_as_uint(v);
  return (u & 0x80000000u) ? ~u : (u | 0x80000000u);
}

// Replicates np.linalg.norm for a 64-elem row (pairwise-8 order), sqrt, max(,1e-12).
__device__ __forceinline__ float np_l2norm_row(const float* __restrict__ x){
  float r[8];
  #pragma unroll
  for (int j=0;j<8;j++){ float t=x[j]; r[j]=__fmul_rn(t,t); }
  #pragma unroll
  for (int b=1;b<8;b++){
    #pragma unroll
    for (int j=0;j<8;j++){ float t=x[b*8+j]; r[j]=__fadd_rn(r[j], __fmul_rn(t,t)); }
  }
  float s = __fadd_rn(__fadd_rn(__fadd_rn(r[0],r[1]),__fadd_rn(r[2],r[3])),
                      __fadd_rn(__fadd_rn(r[4],r[5]),__fadd_rn(r[6],r[7])));
  float nr = __fsqrt_rn(s);
  return fmaxf(nr, 1e-12f);
}

// blocks 0..255: LDS-staged coalesced z row-norms (256 rows/block).
// blocks 256..259: emb normalization into cn + zeroing first 16KB of ws.
__global__ __launch_bounds__(256) void init_kernel(const float* __restrict__ z,
        const float* __restrict__ emb, float* __restrict__ norms,
        float* __restrict__ cn, float* __restrict__ wszero){
  __shared__ float4 zl[256*ZSTRIDE];     // 69,632 B
  const int tid = threadIdx.x;
  if (blockIdx.x < 256){
    const float4* zg = (const float4*)(z + (size_t)blockIdx.x*256*ED);
    #pragma unroll
    for (int i=0;i<16;i++){
      int g = i*256 + tid;               // 0..4095, coalesced
      int row = g>>4, q = g&15;
      zl[row*ZSTRIDE + q] = zg[g];
    }
    __syncthreads();
    const float* xr = (const float*)&zl[tid*ZSTRIDE];
    norms[blockIdx.x*256 + tid] = np_l2norm_row(xr);
  } else {
    int eb = blockIdx.x - 256;           // 0..3
    ((float4*)wszero)[eb*256 + tid] = make_float4(0.f,0.f,0.f,0.f);
    int n = eb*256 + tid;                // < 1024
    float xv[ED];
    const float4* xg = (const float4*)(emb + (size_t)n*ED);
    #pragma unroll
    for (int i=0;i<16;i++) *(float4*)&xv[i*4] = xg[i];
    float nr = np_l2norm_row(xv);
    float4* o = (float4*)(cn + (size_t)n*ED);
    #pragma unroll
    for (int i=0;i<16;i++){
      float4 v;
      v.x=__fdiv_rn(xv[i*4+0],nr); v.y=__fdiv_rn(xv[i*4+1],nr);
      v.z=__fdiv_rn(xv[i*4+2],nr); v.w=__fdiv_rn(xv[i*4+3],nr);
      o[i]=v;
    }
  }
}

// d = zn @ cn^T (65536x1024, K=64) stored transposed dT[c][r].
// LDS-tiled 128x128, 8x8 register blocking, XOR-swizzled LDS, LDS-transposed
// coalesced column stores (R8). z normalized in-staging (bit-exact).
__global__ __launch_bounds__(256) void gemm_kernel(const float* __restrict__ z,
      const float* __restrict__ norms,
      const float* __restrict__ cn, float* __restrict__ dT,
      unsigned long long* __restrict__ rowkey8){
  __shared__ float4 zsh[128*16];   // [r][slot], slot = q ^ ((r>>3)&7); reused as transpose tile
  __shared__ float4 wsh[128*16];   // [c][slot], slot = q ^ (c&7)
  const int tid = threadIdx.x;
  const int rblk = blockIdx.x >> 3;          // 0..511
  const int cblk = blockIdx.x & 7;           // 0..7
  const int r0 = rblk*128, c0g = cblk*128;

  const float4* zg = (const float4*)(z + (size_t)r0*ED);
  const float4* wg = (const float4*)(cn + (size_t)c0g*ED);
  #pragma unroll
  for (int i=0;i<8;i++){
    int di = i*256 + tid;                    // float4 slot 0..2047
    int c = di>>4, q = di&15;
    wsh[di] = wg[c*16 + (q ^ (c&7))];
    float4 zv4 = zg[c*16 + (q ^ ((c>>3)&7))];
    float nr = norms[r0 + c];
    zv4.x=__fdiv_rn(zv4.x,nr); zv4.y=__fdiv_rn(zv4.y,nr);
    zv4.z=__fdiv_rn(zv4.z,nr); zv4.w=__fdiv_rn(zv4.w,nr);
    zsh[di] = zv4;
  }
  __syncthreads();

  const int l  = tid & 63;
  const int wv = tid >> 6;
  const int rg = l >> 4;                     // 0..3
  const int cl = l & 15;                     // 0..15
  const int rowb = wv*32 + rg*8;             // lane's 8 consecutive local rows
  const int zsw = ((rowb>>3)&7);
  const int sw = cl & 7;

  float acc[8][8];
  #pragma unroll
  for (int r=0;r<8;r++)
    #pragma unroll
    for (int j=0;j<8;j++) acc[r][j]=0.0f;

  for (int q=0;q<16;q++){
    float4 zv[8], wvv[8];
    #pragma unroll
    for (int r=0;r<8;r++){
      int row = rowb + r;
      zv[r] = zsh[row*16 + (q ^ zsw)];
    }
    #pragma unroll
    for (int j=0;j<8;j++){
      int c = cl + 16*j;
      wvv[j] = wsh[c*16 + (q ^ sw)];
    }
    #pragma unroll
    for (int r=0;r<8;r++){
      #pragma unroll
      for (int j=0;j<8;j++){
        float a = acc[r][j];
        a = fmaf(zv[r].x, wvv[j].x, a);
        a = fmaf(zv[r].y, wvv[j].y, a);
        a = fmaf(zv[r].z, wvv[j].z, a);
        a = fmaf(zv[r].w, wvv[j].w, a);
        acc[r][j] = a;
      }
    }
  }

  // ---- coalesced transposed store via LDS (4 chunks of 32 columns) ----
  float4* tsh = zsh;                         // [colL][33] float4
  #pragma unroll
  for (int chunk=0;chunk<4;chunk++){
    __syncthreads();
    #pragma unroll
    for (int j2=0;j2<2;j2++){
      int j = chunk*2 + j2;
      int colL = cl + 16*j2;
      tsh[colL*33 + (rowb>>2)]     = make_float4(acc[0][j],acc[1][j],acc[2][j],acc[3][j]);
      tsh[colL*33 + (rowb>>2) + 1] = make_float4(acc[4][j],acc[5][j],acc[6][j],acc[7][j]);
    }
    __syncthreads();
    #pragma unroll
    for (int i=0;i<4;i++){
      int f = tid + 256*i;                   // 0..1023
      int colL = f >> 5, r4 = f & 31;
      int col = c0g + chunk*32 + colL;
      *(float4*)(dT + (size_t)col*NF + r0 + 4*r4) = tsh[colL*33 + r4];
    }
  }

  #pragma unroll
  for (int r=0;r<8;r++){
    float bv = acc[r][0]; int bc = c0g + cl;
    #pragma unroll
    for (int j=1;j<8;j++){
      int c = c0g + cl + 16*j;
      if (acc[r][j] > bv){ bv = acc[r][j]; bc = c; }
    }
    unsigned long long key = ((unsigned long long)ordf(bv)<<32) |
                             (unsigned long long)(0xFFFFFFFFu - (unsigned)bc);
    #pragma unroll
    for (int m=1;m<16;m<<=1){
      unsigned long long o = __shfl_xor(key, m);
      if (o > key) key = o;
    }
    if (cl==0) rowkey8[(size_t)(r0 + rowb + r)*8 + cblk] = key;
  }
}

// Merged dispatch: blocks 0..1023 = colstats (two-pass strided streams,
// sortless selection, fused nontemporal zero-write, __expf hot loops).
// blocks 1024..2047 = zq work.
__global__ __launch_bounds__(1024) void colstats_zq_kernel(float* __restrict__ dT,
        int* __restrict__ anchor, double* __restrict__ accs,
        const float* __restrict__ z, const float* __restrict__ emb,
        const unsigned long long* __restrict__ rowkey8,
        int* __restrict__ counts, float* __restrict__ out){
  __shared__ unsigned hist[BINS];
  __shared__ float bufB[CAPB];
  __shared__ float bufT[CAPT];
  __shared__ float bndry[CAP3];
  __shared__ unsigned wtot[16];
  __shared__ float wred[16];
  __shared__ float s_m0f;
  __shared__ int s_anch;
  __shared__ int s_binB, s_cbelow, s_binT;
  __shared__ int s_cntB, s_cntT, s_cnt3;
  __shared__ int s_binB2, s_cb2, s_binT2, s_ca2;
  __shared__ float s_Ebelow, s_EbinPre, s_acc3B, s_TopPre, s_acc3T;

  const int tid = threadIdx.x;
  const int lane = tid & 63;
  const int wid = tid >> 6;           // 0..15

  if (blockIdx.x >= 1024){
    // ================= zq branch =================
    const int gid = (blockIdx.x - 1024)*1024 + tid;   // < 1048576 float4 units
    const int f = gid >> 4;
    const int sub = gid & 15;
    int c = 0;
    if (sub == 0){
      const unsigned long long* rk = rowkey8 + (size_t)f*8;
      unsigned long long K = rk[0];
      #pragma unroll
      for (int w=1;w<8;w++){
        unsigned long long o = rk[w];
        if (o > K) K = o;
      }
      c = (int)(0xFFFFFFFFu - (unsigned)(K & 0xFFFFFFFFull));
      out[OFF_IDX + f] = (float)c;
      atomicAdd(&counts[c], 1);
    }
    c = __shfl(c, lane & ~15);
    const int e0 = sub*4;
    const float4 q = *(const float4*)(emb + (size_t)c*ED + e0);
    const float4 zv = ((const float4*)z)[gid];
    float dx=__fsub_rn(q.x,zv.x), dy=__fsub_rn(q.y,zv.y);
    float dz2=__fsub_rn(q.z,zv.z), dw=__fsub_rn(q.w,zv.w);
    float ox=__fadd_rn(zv.x,dx), oy=__fadd_rn(zv.y,dy);
    float oz=__fadd_rn(zv.z,dz2), ow=__fadd_rn(zv.w,dw);
    size_t base = (size_t)gid*4;
    float* zq = out + OFF_ZQST; float* zo = out + OFF_ZOUT;
    zq[base+0]=ox; zq[base+1]=oy; zq[base+2]=oz; zq[base+3]=ow;
    zo[base+0]=ox; zo[base+1]=oy; zo[base+2]=oz; zo[base+3]=ow;
    float ls = __fadd_rn(__fadd_rn(__fmul_rn(dx,dx),__fmul_rn(dy,dy)),
                         __fadd_rn(__fmul_rn(dz2,dz2),__fmul_rn(dw,dw)));
    #pragma unroll
    for (int off=32;off;off>>=1) ls += __shfl_down(ls, off);
    if (lane==0) wred[wid]=ls;
    __syncthreads();
    if (tid==0){
      float t=wred[0];
      #pragma unroll
      for (int w=1;w<16;w++) t+=wred[w];
      atomicAdd(&accs[0], (double)t);
    }
    return;
  }

  // ================= colstats branch =================
  const int n = blockIdx.x;
  float* __restrict__ p = dT + (size_t)n*NF;
  const float4* __restrict__ p4c = (const float4*)p;

  hist[tid]=0u; hist[tid+1024]=0u;
  if (tid==0){ s_cntB=0; s_cntT=0; s_anch=0x7FFFFFFF; }
  __syncthreads();

  // ---- pass 1 (strided float4): histogram + max ----
  float mx = -INFINITY;
  for (int i4=tid;i4<NF/4;i4+=1024){
    float4 v4 = p4c[i4];
    #pragma unroll
    for (int c=0;c<4;c++){
      float v = (c==0)?v4.x:(c==1)?v4.y:(c==2)?v4.z:v4.w;
      mx = fmaxf(mx, v);
      int b = (int)((v+1.0f)*1024.0f);
      b = b<0?0:(b>BINS-1?BINS-1:b);
      atomicAdd(&hist[b],1u);
    }
  }
  #pragma unroll
  for (int off=32;off;off>>=1) mx = fmaxf(mx, __shfl_down(mx, off));
  if (lane==0) wred[wid]=mx;
  __syncthreads();
  if (tid==0){
    float t=wred[0];
    #pragma unroll
    for (int w=1;w<16;w++) t=fmaxf(t,wred[w]);
    s_m0f = t;
  }

  // ---- level-1 scan over bin-pairs (2 syncs) ----
  const unsigned h0 = hist[2*tid], h1 = hist[2*tid+1];
  const unsigned c2 = h0+h1;
  unsigned x = c2;
  #pragma unroll
  for (int off=1;off<64;off<<=1){
    unsigned y = __shfl_up(x, off);
    if (lane >= off) x += y;
  }
  if (lane==63) wtot[wid] = x;
  __syncthreads();
  if (wid==0 && lane<16){
    unsigned t = wtot[lane];
    #pragma unroll
    for (int off=1;off<16;off<<=1){
      unsigned y = __shfl_up(t, off);
      if (lane >= off) t += y;
    }
    wtot[lane] = t;
  }
  __syncthreads();
  const unsigned inc1 = x + (wid>0 ? wtot[wid-1] : 0u);
  {
    const unsigned pre = inc1 - c2;
    if (pre < (unsigned)KBOT && pre+h0 >= (unsigned)KBOT){ s_binB=2*tid;   s_cbelow=(int)pre; }
    else if (pre+h0 < (unsigned)KBOT && inc1 >= (unsigned)KBOT){ s_binB=2*tid+1; s_cbelow=(int)(pre+h0); }
    if (pre <= (unsigned)RTOP && (unsigned)RTOP < pre+h0) s_binT=2*tid;
    else if (pre+h0 <= (unsigned)RTOP && (unsigned)RTOP < inc1) s_binT=2*tid+1;
  }
  __syncthreads();

  // ---- pass 2: E_below + gather + anchor + fused zero-write ----
  const int binB=s_binB, binT=s_binT;
  const float m0=s_m0f;
  const float LINV = 1.0f/0.07f;
  nvec4 zz = (nvec4)(0.0f);
  nvec4* p4w = (nvec4*)p;
  float es=0.0f;
  for (int i4=tid;i4<NF/4;i4+=1024){
    float4 v4 = p4c[i4];
    __builtin_nontemporal_store(zz, &p4w[i4]);
    int base = i4*4;
    #pragma unroll
    for (int c=0;c<4;c++){
      float v = (c==0)?v4.x:(c==1)?v4.y:(c==2)?v4.z:v4.w;
      int b=(int)((v+1.0f)*1024.0f);
      b=b<0?0:(b>BINS-1?BINS-1:b);
      if (b<binB) es += __expf((v-m0)*LINV);
      if (b==binB){ int pos=atomicAdd(&s_cntB,1); if (pos<CAPB) bufB[pos]=v; }
      if (b>=binT){ int pos=atomicAdd(&s_cntT,1); if (pos<CAPT) bufT[pos]=v; }
      if (v==m0) atomicMin(&s_anch, base+c);
    }
  }
  hist[tid]=0u; hist[tid+1024]=0u;
  #pragma unroll
  for (int off=32;off;off>>=1) es += __shfl_down(es, off);
  if (lane==0) wred[wid]=es;
  __syncthreads();
  if (tid==0){
    float t=wred[0];
    #pragma unroll
    for (int w=1;w<16;w++) t+=wred[w];
    s_Ebelow=t;
    s_cnt3=0; s_binB2=0; s_cb2=0; s_acc3B=0.0f; s_acc3T=0.0f;
  }
  __syncthreads();

  // ---- level-2 bottom ----
  const int cntB = (s_cntB<CAPB)?s_cntB:CAPB;
  int m = KBOT - s_cbelow; if (m>cntB) m=cntB; if (m<0) m=0;
  const float loB = (float)binB*(1.0f/1024.0f) - 1.0f;
  float* fsum = (float*)&hist[1024];
  for (int i=tid;i<cntB;i+=1024){
    float v=bufB[i];
    int sub=(int)((v-loB)*1048576.0f);
    sub = sub<0?0:(sub>1023?1023:sub);
    atomicAdd(&hist[sub],1u);
    atomicAdd(&fsum[sub], __expf((v-m0)*LINV));
  }
  __syncthreads();
  {
    unsigned cb = hist[tid];
    unsigned xb = cb;
    #pragma unroll
    for (int off=1;off<64;off<<=1){
      unsigned y = __shfl_up(xb, off);
      if (lane >= off) xb += y;
    }
    if (lane==63) wtot[wid]=xb;
    __syncthreads();
    if (wid==0 && lane<16){
      unsigned t = wtot[lane];
      #pragma unroll
      for (int off=1;off<16;off<<=1){
        unsigned y = __shfl_up(t, off);
        if (lane >= off) t += y;
      }
      wtot[lane]=t;
    }
    __syncthreads();
    unsigned incb = xb + (wid>0? wtot[wid-1]:0u);
    unsigned preb = incb - cb;
    if (m>0 && preb < (unsigned)m && incb >= (unsigned)m){ s_binB2=tid; s_cb2=(int)preb; }
  }
  __syncthreads();
  {
    float ep = (tid < s_binB2)? fsum[tid] : 0.0f;
    #pragma unroll
    for (int off=32;off;off>>=1) ep += __shfl_down(ep, off);
    if (lane==0) wred[wid]=ep;
    __syncthreads();
    if (tid==0){
      float t=wred[0];
      #pragma unroll
      for (int w=1;w<16;w++) t+=wred[w];
      s_EbinPre=t;
    }
  }
  const int binB2=s_binB2;
  const int m2v = m - s_cb2;
  for (int i=tid;i<cntB;i+=1024){
    float v=bufB[i];
    int sub=(int)((v-loB)*1048576.0f);
    sub = sub<0?0:(sub>1023?1023:sub);
    if (sub==binB2){ int pos=atomicAdd(&s_cnt3,1); if (pos<CAP3) bndry[pos]=v; }
  }
  __syncthreads();
  if (wid==0){
    int cnt3 = (s_cnt3<CAP3)?s_cnt3:CAP3;
    int m2 = m2v; if (m2>cnt3) m2=cnt3; if (m2<0) m2=0;
    float acc3=0.0f;
    for (int it=0; it<m2; ++it){
      unsigned long long key = 0ull;
      for (int i=lane;i<cnt3;i+=64){
        float v=bndry[i];
        unsigned long long k = ((unsigned long long)(0xFFFFFFFFu - ordf(v))<<32) | (unsigned)i;
        if (k>key) key=k;
      }
      #pragma unroll
      for (int off=32;off;off>>=1){
        unsigned long long o = __shfl_xor(key, off);
        if (o>key) key=o;
      }
      int idx = (int)(key & 0xFFFFFFFFull);
      if (lane==0){
        float v = bndry[idx];
        acc3 += __expf((v-m0)*LINV);
        bndry[idx] = __uint_as_float(0x7f800000u);
      }
    }
    if (lane==0) s_acc3B = acc3;
  }
  hist[tid]=0u; hist[tid+1024]=0u;
  if (tid==1023) s_cnt3=0;
  __syncthreads();

  // ---- level-2 top ----
  const int cntT = (s_cntT<CAPT)?s_cntT:CAPT;
  const float loT = (float)binT*(1.0f/1024.0f) - 1.0f;
  float rngT = m0 - loT;
  float scaleT = (rngT > 1e-30f)? (1023.0f/rngT) : 0.0f;
  for (int i=tid;i<cntT;i+=1024){
    float v=bufT[i];
    int sub=(int)((v-loT)*scaleT);
    sub = sub<0?0:(sub>1023?1023:sub);
    atomicAdd(&hist[sub],1u);
    atomicAdd(&fsum[sub], v);
  }
  __syncthreads();
  {
    unsigned ct = hist[tid];
    unsigned xt = ct;
    #pragma unroll
    for (int off=1;off<64;off<<=1){
      unsigned y = __shfl_up(xt, off);
      if (lane >= off) xt += y;
    }
    if (lane==63) wtot[wid]=xt;
    __syncthreads();
    if (wid==0 && lane<16){
      unsigned t = wtot[lane];
      #pragma unroll
      for (int off=1;off<16;off<<=1){
        unsigned y = __shfl_up(t, off);
        if (lane >= off) t += y;
      }
      wtot[lane]=t;
    }
    __syncthreads();
    unsigned inct = xt + (wid>0? wtot[wid-1]:0u);
    unsigned above = (unsigned)cntT - inct;
    if (above < 64u && above + ct >= 64u){ s_binT2=tid; s_ca2=(int)above; }
  }
  __syncthreads();
  {
    float tv = (tid > s_binT2)? fsum[tid] : 0.0f;
    #pragma unroll
    for (int off=32;off;off>>=1) tv += __shfl_down(tv, off);
    if (lane==0) wred[wid]=tv;
    __syncthreads();
    if (tid==0){
      float t=wred[0];
      #pragma unroll
      for (int w=1;w<16;w++) t+=wred[w];
      s_TopPre=t;
    }
  }
  const int binT2=s_binT2;
  const int need2v = 64 - s_ca2;
  for (int i=tid;i<cntT;i+=1024){
    float v=bufT[i];
    int sub=(int)((v-loT)*scaleT);
    sub = sub<0?0:(sub>1023?1023:sub);
    if (sub==binT2){ int pos=atomicAdd(&s_cnt3,1); if (pos<CAP3) bndry[pos]=v; }
  }
  __syncthreads();
  if (wid==0){
    int cnt3 = (s_cnt3<CAP3)?s_cnt3:CAP3;
    int need2 = need2v; if (need2>cnt3) need2=cnt3; if (need2<0) need2=0;
    float acc3=0.0f;
    for (int it=0; it<need2; ++it){
      unsigned long long key = 0ull;
      for (int i=lane;i<cnt3;i+=64){
        float v=bndry[i];
        unsigned long long k = ((unsigned long long)ordf(v)<<32) | (unsigned)i;
        if (k>key) key=k;
      }
      #pragma unroll
      for (int off=32;off;off>>=1){
        unsigned long long o = __shfl_xor(key, off);
        if (o>key) key=o;
      }
      int idx = (int)(key & 0xFFFFFFFFull);
      if (lane==0){
        acc3 += bndry[idx];
        bndry[idx] = __uint_as_float(0xff800000u);
      }
    }
    if (lane==0) s_acc3T = acc3;
  }
  __syncthreads();
  if (tid==0){
    float topSum = s_TopPre + s_acc3T;
    float dis_pos = topSum*(1.0f/64.0f);
    float S = (s_Ebelow + s_EbinPre + s_acc3B)*expf((m0-dis_pos)*LINV);
    atomicAdd(&accs[1], (double)log1pf(S));
    anchor[n] = s_anch;
  }
}

// blocks 0..255: codebook update (4 columns per block).
// blocks 256..511: one-hot scatter. Last block to finish runs finalize.
__global__ __launch_bounds__(256) void codebook_scatter_kernel(const float* __restrict__ emb,
     const float* __restrict__ eprob, const float* __restrict__ z,
     const int* __restrict__ counts, const int* __restrict__ anchor,
     float* __restrict__ out, double* __restrict__ accs, unsigned* __restrict__ done){
  const int b = blockIdx.x;
  if (b < 256){
    const int n = b*4 + (threadIdx.x>>6);
    const int e = threadIdx.x & 63;
    float em = (float)counts[n] * (1.0f/65536.0f);
    float nep = __fadd_rn(__fmul_rn(eprob[n],0.99f), __fmul_rn(em,0.01f));
    if (e==0){
      out[OFF_NEP + n] = nep;
      atomicAdd(&accs[2], (double)__fmul_rn(em, logf(__fadd_rn(em,1e-10f))));
    }
    float t = __fmul_rn(__fmul_rn(nep,1024.0f),10.0f);
    t = __fdiv_rn(-t, 0.01f);
    t = __fsub_rn(t, 0.001f);
    float dec = expf(t);
    float onem = __fsub_rn(1.0f, dec);
    int a = anchor[n];
    float nv = __fadd_rn(__fmul_rn(emb[(size_t)n*ED+e], onem),
                         __fmul_rn(z[(size_t)a*ED+e], dec));
    out[OFF_NEMB + (size_t)n*ED + e] = nv;
  } else {
    int f = (b-256)*256 + threadIdx.x;       // < 65536
    int c = (int)out[OFF_IDX + f];
    out[OFF_MINENC + (size_t)f*NE + c] = 1.0f;
  }
  // ---- last-block finalize ----
  __syncthreads();
  if (threadIdx.x==0){
    __threadfence();
    unsigned prev = atomicAdd(done, 1u);
    if (prev == 511u){
      __threadfence();
      volatile double* va = accs;
      double a0 = va[0], a1 = va[1], a2 = va[2];
      float l1 = (float)(a0 / 4194304.0);
      float contra = (float)(a1 / 1024.0);
      out[OFF_LOSS1]=l1; out[OFF_LOSS2]=l1;
      out[OFF_LOSS]=__fadd_rn(__fadd_rn(__fmul_rn(1.0f,l1), __fmul_rn(0.25f,l1)), contra);
      out[OFF_PERP]=expf(-(float)a2);
    }
  }
}

extern "C" void kernel_launch(void* const* d_in, const int* in_sizes, int n_in,
                              void* d_out, int out_size, void* d_ws, size_t ws_size,
                              hipStream_t stream){
  (void)in_sizes; (void)n_in; (void)out_size; (void)ws_size;
  const float* z    = (const float*)d_in[0];
  const float* emb  = (const float*)d_in[1];
  const float* eprb = (const float*)d_in[2];
  float* out = (float*)d_out;
  char* ws = (char*)d_ws;
  double* accs = (double*)ws;                 // [0]=lossSum [1]=contraSum [2]=perpSum
  int* counts = (int*)(ws + 64);              // 1024 ints
  int* anchor = (int*)(ws + 8192);            // 1024 ints
  unsigned* done = (unsigned*)(ws + 12288);   // finalize counter (zeroed by init)
  float* norms = (float*)(ws + 65536);        // 65536 floats (256KB)
  unsigned long long* rowkey8 = (unsigned long long*)(ws + (1<<20));  // 4MB
  float* cn = out + OFF_IDX;                  // scratch (overwritten by idx floats)
  float* dT = out + OFF_MINENC;               // scratch (becomes min_encodings)

  hipLaunchKernelGGL(init_kernel, dim3(260), dim3(256), 0, stream, z, emb, norms, cn, (float*)ws);
  hipLaunchKernelGGL(gemm_kernel, dim3(4096), dim3(256), 0, stream, z, norms, cn, dT, rowkey8);
  hipLaunchKernelGGL(colstats_zq_kernel, dim3(2048), dim3(1024), 0, stream,
                     dT, anchor, accs, z, emb, rowkey8, counts, out);
  hipLaunchKernelGGL(codebook_scatter_kernel, dim3(512), dim3(256), 0, stream,
                     emb, eprb, z, counts, anchor, out, accs, done);
}